// Round 12
// baseline (253.334 us; speedup 1.0000x reference)
//
#include <hip/hip_runtime.h>
#include <hip/hip_bf16.h>
#include <math.h>

#define BATCH 2
#define SEQ   2048
#define DMODEL 1024
#define NHEADS 16
#define HDIM  64
#define MROWS (BATCH*SEQ)   // 4096
#define QSCALE 0.1803368801111204f   // 0.125 * log2(e); attention uses exp2

typedef __attribute__((ext_vector_type(8))) short bfr8;   // 8 bf16 (4 VGPRs)
typedef __attribute__((ext_vector_type(4))) float f32x4;  // MFMA C/D

__device__ inline unsigned short f2bf(float f) {
    union { float f; unsigned u; } v; v.f = f;
    unsigned r = v.u + 0x7FFFu + ((v.u >> 16) & 1u);   // RNE
    return (unsigned short)(r >> 16);
}

__device__ inline unsigned pack2bf(float a, float b) {   // low=a, high=b
    union { __hip_bfloat162 h; unsigned u; } cv;
    cv.h = __float22bfloat162_rn(float2{a, b});
    return cv.u;
}

__device__ inline void gload16(const unsigned short* g, unsigned short* l) {
    __builtin_amdgcn_global_load_lds((const __attribute__((address_space(1))) void*)g,
        (__attribute__((address_space(3))) void*)l, 16, 0, 0);
}

// ---------------- casts fp32 -> bf16 ----------------
__global__ __launch_bounds__(256) void cast_bf16(const float* __restrict__ in,
                                                 unsigned short* __restrict__ out, int n) {
    int i = (blockIdx.x * 256 + threadIdx.x) * 4;
    const int stride = gridDim.x * 256 * 4;
    for (; i < n; i += stride) {
        float4 v = *(const float4*)(in + i);
        ushort4 o;
        o.x = f2bf(v.x); o.y = f2bf(v.y); o.z = f2bf(v.z); o.w = f2bf(v.w);
        *(ushort4*)(out + i) = o;
    }
}

// 4 weight matrices (each 2^20 elems) -> contiguous dst
__global__ __launch_bounds__(256) void cast4_bf16(
    const float* __restrict__ a, const float* __restrict__ b,
    const float* __restrict__ c, const float* __restrict__ d,
    unsigned short* __restrict__ out) {
    const int NW = 1 << 20;
    int i = (blockIdx.x * 256 + threadIdx.x) * 4;
    const int stride = gridDim.x * 256 * 4;
    for (; i < 4 * NW; i += stride) {
        const int seg = i >> 20;
        const float* src = seg == 0 ? a : seg == 1 ? b : seg == 2 ? c : d;
        float4 v = *(const float4*)(src + (i & (NW - 1)));
        ushort4 o;
        o.x = f2bf(v.x); o.y = f2bf(v.y); o.z = f2bf(v.z); o.w = f2bf(v.w);
        *(ushort4*)(out + i) = o;
    }
}

// ---------------- bf16 MFMA GEMM: Y = A @ W^T + bias ----------------
// Tile BM x 128, BK=32, 4 waves. 3-buffer LDS, depth-2 prefetch, SOUND sync:
// {vmcnt(own tile-t loads); s_barrier} THEN stage(t+2) THEN compute.
// MODE 0: N=3072 fused QKV; XCD rect remap (12 x gridDim.y/4 per XCD);
//         Q scaled; Q,K->[B,H,T,64], V->[B,H,64,T]
// MODE 2: N=1024, fp32 linear output [4096,1024], bias b0
template<int BM, int MODE>
__global__ __launch_bounds__(256) void gemm_bf16(
    const unsigned short* __restrict__ A, const unsigned short* __restrict__ W,
    const float* __restrict__ b0, const float* __restrict__ b1,
    const float* __restrict__ b2, void* __restrict__ Y)
{
    __shared__ __align__(16) unsigned short As[3][4][BM][8];
    __shared__ __align__(16) unsigned short Bs[3][4][128][8];

    constexpr int NT  = 32;            // K / 32
    constexpr int NLD = BM / 64 + 2;   // gload_lds instrs per thread per stage

    const int tid = threadIdx.x;
    const int l = tid & 63, w = tid >> 6;
    const int wr = w >> 1, wc = w & 1;
    const int r15 = l & 15, g = l >> 4;
    constexpr int MR = BM / 32;

    // block remap: MODE 0 (grid 24 x GY) -> each XCD (flat&7) owns a 12 x GY/4 rect.
    int bx, by;
    if (MODE == 0) {
        const int flat = blockIdx.x + blockIdx.y * 24;
        const int xcd = flat & 7, s = flat >> 3;        // s in [0, 3*GY)
        const int rpx = gridDim.y >> 2;                 // rect rows per XCD
        bx = (xcd & 1) * 12 + s % 12;
        by = (xcd >> 1) * rpx + s / 12;
    } else {
        bx = blockIdx.x; by = blockIdx.y;
    }
    const int m0 = by * BM, n0 = bx * 128;

    f32x4 acc[MR][4] = {};

    auto stage = [&](int buf, int t) {
        const int k0 = t * 32;
        #pragma unroll
        for (int s = 0; s < BM / 64; ++s) {
            int idx = s * 256 + tid;
            int row = idx % BM, kg = idx / BM;
            gload16(A + (size_t)(m0 + row) * 1024 + k0 + kg * 8, &As[buf][kg][row][0]);
        }
        #pragma unroll
        for (int s = 0; s < 2; ++s) {
            int idx = s * 256 + tid;
            int row = idx & 127, kg = idx >> 7;
            gload16(W + (size_t)(n0 + row) * 1024 + k0 + kg * 8, &Bs[buf][kg][row][0]);
        }
    };

    stage(0, 0);
    stage(1, 1);

    for (int t = 0; t < NT; ++t) {
        // SOUND order: each wave waits for ITS OWN tile-t loads, then barrier
        // publishes "all waves' tile-t landed" + "all finished compute(t-1)".
        if (t < NT - 1)
            asm volatile("s_waitcnt vmcnt(%0)\ns_barrier" :: "n"(NLD) : "memory");
        else
            asm volatile("s_waitcnt vmcnt(0)\ns_barrier" ::: "memory");
        if (t + 2 < NT) stage((t + 2) % 3, t + 2);

        const int buf = t % 3;
        bfr8 a[MR], b[4];
        #pragma unroll
        for (int m = 0; m < MR; ++m)
            a[m] = *(const bfr8*)&As[buf][g][wr * (BM / 2) + m * 16 + r15][0];
        #pragma unroll
        for (int n = 0; n < 4; ++n)
            b[n] = *(const bfr8*)&Bs[buf][g][wc * 64 + n * 16 + r15][0];
        #pragma unroll
        for (int m = 0; m < MR; ++m)
            #pragma unroll
            for (int n = 0; n < 4; ++n)
                acc[m][n] = __builtin_amdgcn_mfma_f32_16x16x32_bf16(a[m], b[n], acc[m][n], 0, 0, 0);
    }

    const size_t NX = (size_t)MROWS * DMODEL;
    #pragma unroll
    for (int m = 0; m < MR; ++m) {
        const int rowb = m0 + wr * (BM / 2) + m * 16 + g * 4;
        #pragma unroll
        for (int n = 0; n < 4; ++n) {
            const int col = n0 + wc * 64 + n * 16 + r15;
            const int proj = col >> 10, within = col & 1023;
            const float bc = (MODE == 2) ? b0[col]
                           : (proj == 0 ? b0[within] : proj == 1 ? b1[within] : b2[within]);
            #pragma unroll
            for (int i = 0; i < 4; ++i) {
                float v = acc[m][n][i] + bc;
                const int rr = rowb + i;
                if (MODE == 2) {
                    ((float*)Y)[(size_t)rr * 1024 + col] = v;
                } else {
                    if (proj == 0) v *= QSCALE;
                    const int bb = rr >> 11, tt = rr & 2047;
                    const int hh = within >> 6, dd = within & 63;
                    unsigned short* dst = (unsigned short*)Y + (size_t)proj * NX;
                    size_t idx;
                    if (proj < 2)
                        idx = (((size_t)bb * NHEADS + hh) * SEQ + tt) * HDIM + dd;
                    else
                        idx = (((size_t)bb * NHEADS + hh) * HDIM + dd) * SEQ + tt;
                    dst[idx] = f2bf(v);
                }
            }
        }
    }
}

// ---------------- MFMA flash attention (causal, fully lane-local softmax) ----------------
// [R6 structure EXACT: 2-buffer, 40KB LDS, 4 blocks/CU, __syncthreads drain — ~40µs;
//  R11's barrier-free L2-direct variant measured 122µs (latency-chain bound) — reverted]
__global__ __launch_bounds__(256, 4) void attn_mfma(
    const unsigned short* __restrict__ Q, const unsigned short* __restrict__ K,
    const unsigned short* __restrict__ VT, unsigned short* __restrict__ O)
{
    __shared__ __align__(16) unsigned short Ks[2][64][64];   // [kv][d] granule-swizzled (16K)
    __shared__ __align__(16) unsigned short Vs[2][64][64];   // [d][kv] granule-swizzled (16K)
    __shared__ __align__(16) unsigned short Ps[4][8][16][8]; // [wave][kg][q][e]  (8K)

    const int tid = threadIdx.x;
    const int l = tid & 63, w = tid >> 6;
    const int r15 = l & 15, g2 = l >> 4;          // g2 = 0..3
    const int qt = (blockIdx.x + blockIdx.y) & 31;   // decorrelate length from CU
    const int q0 = SEQ - 64 - qt * 64;
    const int q  = q0 + w * 16 + r15;             // this lane's q column
    const int bh = blockIdx.y;

    const unsigned short* Qb = Q + (size_t)bh * SEQ * HDIM;
    const unsigned short* Kb = K + (size_t)bh * SEQ * HDIM;
    const unsigned short* Vb = VT + (size_t)bh * HDIM * SEQ;

    bfr8 qf[2];
    qf[0] = *(const bfr8*)(Qb + (size_t)q * HDIM + g2 * 8);
    qf[1] = *(const bfr8*)(Qb + (size_t)q * HDIM + 32 + g2 * 8);

    auto stage = [&](int buf, int kv0) {
        #pragma unroll
        for (int s = 0; s < 2; ++s) {
            int idx = s * 256 + tid;               // 512 granules each of K, V
            int row = idx >> 3, gs = idx & 7;
            gload16(Kb + (size_t)(kv0 + row) * HDIM + ((gs ^ (row & 7)) * 8), &Ks[buf][row][gs * 8]);
            gload16(Vb + (size_t)row * SEQ + kv0 + ((gs ^ (row & 7)) * 8), &Vs[buf][row][gs * 8]);
        }
    };

    f32x4 o[4] = {};                 // o[ch][i]: d = ch*16 + g2*4 + i, col q
    float m = -INFINITY, rden = 0.f;

    const int ntiles = q0 / 64 + 1;
    stage(0, 0);
    __syncthreads();

    for (int kt = 0; kt < ntiles; ++kt) {
        const int kv0 = kt * 64, buf = kt & 1;
        if (kt + 1 < ntiles) stage(buf ^ 1, kv0 + 64);

        // ---- S^T = K @ Q^T : s[c][i], kv = c*16 + g2*4 + i, q = col r15 ----
        f32x4 s[4];
        #pragma unroll
        for (int c = 0; c < 4; ++c) {
            const int rk = c * 16 + r15;
            const bfr8 kf0 = *(const bfr8*)&Ks[buf][rk][(g2 ^ (r15 & 7)) * 8];
            const bfr8 kf1 = *(const bfr8*)&Ks[buf][rk][((4 + g2) ^ (r15 & 7)) * 8];
            f32x4 z = {0.f, 0.f, 0.f, 0.f};
            z = __builtin_amdgcn_mfma_f32_16x16x32_bf16(kf0, qf[0], z, 0, 0, 0);
            s[c] = __builtin_amdgcn_mfma_f32_16x16x32_bf16(kf1, qf[1], z, 0, 0, 0);
        }

        if (kt == ntiles - 1) {      // causal mask: only the diagonal tile
            #pragma unroll
            for (int c = 0; c < 4; ++c)
                #pragma unroll
                for (int i = 0; i < 4; ++i)
                    if (kv0 + c * 16 + g2 * 4 + i > q) s[c][i] = -INFINITY;
        }

        // ---- lane-local online softmax with defer-max ----
        float tm = s[0][0];
        #pragma unroll
        for (int c = 0; c < 4; ++c)
            #pragma unroll
            for (int i = 0; i < 4; ++i) tm = fmaxf(tm, s[c][i]);
        tm = fmaxf(tm, __shfl_xor(tm, 16));
        tm = fmaxf(tm, __shfl_xor(tm, 32));
        if (__any(tm > m + 8.f)) {            // rescale (always taken on first tile)
            const float mn = fmaxf(m, tm);
            const float scl = exp2f(m - mn);  // 0 on first tile
            m = mn;
            rden *= scl;
            #pragma unroll
            for (int ch = 0; ch < 4; ++ch)
                #pragma unroll
                for (int i = 0; i < 4; ++i) o[ch][i] *= scl;
        }
        float ls = 0.f;
        #pragma unroll
        for (int c = 0; c < 4; ++c)
            #pragma unroll
            for (int i = 0; i < 4; ++i) {
                const float p = exp2f(s[c][i] - m);
                s[c][i] = p;
                ls += p;
            }
        ls += __shfl_xor(ls, 16);
        ls += __shfl_xor(ls, 32);
        rden += ls;

        // ---- P -> LDS in B-frag layout: Ps[kg][q][e] = P[kv=kg*8+e][q] ----
        {
            const int eb = (g2 & 1) * 4;
            #pragma unroll
            for (int c = 0; c < 4; ++c) {
                const int kg = c * 2 + (g2 >> 1);
                *(unsigned*)&Ps[w][kg][r15][eb]     = pack2bf(s[c][0], s[c][1]);
                *(unsigned*)&Ps[w][kg][r15][eb + 2] = pack2bf(s[c][2], s[c][3]);
            }
        }
        // wave-private buffer: within-wave lgkmcnt ordering suffices (no barrier)
        bfr8 pf[2];
        pf[0] = *(const bfr8*)&Ps[w][g2][r15][0];
        pf[1] = *(const bfr8*)&Ps[w][4 + g2][r15][0];

        // ---- O' += V^T @ P ----
        #pragma unroll
        for (int ch = 0; ch < 4; ++ch) {
            const int d = ch * 16 + r15;
            const bfr8 vf0 = *(const bfr8*)&Vs[buf][d][(g2 ^ (r15 & 7)) * 8];
            const bfr8 vf1 = *(const bfr8*)&Vs[buf][d][((4 + g2) ^ (r15 & 7)) * 8];
            o[ch] = __builtin_amdgcn_mfma_f32_16x16x32_bf16(vf0, pf[0], o[ch], 0, 0, 0);
            o[ch] = __builtin_amdgcn_mfma_f32_16x16x32_bf16(vf1, pf[1], o[ch], 0, 0, 0);
        }
        __syncthreads();   // protect K/V buffers (also drains staged loads)
    }

    const float inv = 1.f / rden;
    const int b = bh >> 4, h = bh & 15;
    unsigned short* Ob = O + ((size_t)b * SEQ + q) * DMODEL + h * HDIM + g2 * 4;
    #pragma unroll
    for (int ch = 0; ch < 4; ++ch) {
        uint2 pk;
        pk.x = pack2bf(o[ch][0] * inv, o[ch][1] * inv);
        pk.y = pack2bf(o[ch][2] * inv, o[ch][3] * inv);
        *(uint2*)(Ob + ch * 16) = pk;
    }
}

// ---------------- launch ----------------
extern "C" void kernel_launch(void* const* d_in, const int* in_sizes, int n_in,
                              void* d_out, int out_size, void* d_ws, size_t ws_size,
                              hipStream_t stream) {
    const float* x   = (const float*)d_in[0];
    const float* w_q = (const float*)d_in[1];
    const float* b_q = (const float*)d_in[2];
    const float* w_k = (const float*)d_in[3];
    const float* b_k = (const float*)d_in[4];
    const float* w_v = (const float*)d_in[5];
    const float* b_v = (const float*)d_in[6];
    const float* w_o = (const float*)d_in[7];
    const float* b_o = (const float*)d_in[8];
    float* out = (float*)d_out;

    const size_t NX = (size_t)MROWS * DMODEL;   // 4,194,304
    const size_t NW = (size_t)DMODEL * DMODEL;  // 1,048,576 = 2^20
    unsigned short* xb    = (unsigned short*)d_ws;
    unsigned short* wcomb = xb + NX;            // [3072][1024] = wq|wk|wv, then wo
    unsigned short* wob   = wcomb + 3 * NW;
    unsigned short* Qw    = wob + NW;           // [B,H,T,64] (scaled)
    unsigned short* Kw    = Qw + NX;            // [B,H,T,64]
    unsigned short* VTw   = Kw + NX;            // [B,H,64,T]
    unsigned short* Ow    = VTw + NX;           // [B,T,1024]

    cast_bf16<<<1024, 256, 0, stream>>>(x, xb, (int)NX);
    cast4_bf16<<<2048, 256, 0, stream>>>(w_q, w_k, w_v, w_o, wcomb);

    // QKV projection A/B (idempotent, both write same outputs):
    //   Va: BM=128 (3 blocks/CU, 16 MFMA/wave/iter)  — R11 baseline ~65µs
    //   Vb: BM=64  (6 blocks/CU, 8 MFMA/wave/iter)   — TLP hypothesis
    gemm_bf16<128, 0><<<dim3(24, 32), 256, 0, stream>>>(xb, wcomb, b_q, b_k, b_v, Qw);
    gemm_bf16<64,  0><<<dim3(24, 64), 256, 0, stream>>>(xb, wcomb, b_q, b_k, b_v, Qw);

    attn_mfma<<<dim3(32, 32), 256, 0, stream>>>(Qw, Kw, VTw, Ow);

    // output projection: [4096,1024] @ [1024,1024]^T -> fp32
    gemm_bf16<64, 2><<<dim3(8, 64), 256, 0, stream>>>(Ow, wob, b_o, nullptr, nullptr, out);
}

// Round 13
// 184.624 us; speedup vs baseline: 1.3722x; 1.3722x over previous
//
#include <hip/hip_runtime.h>
#include <hip/hip_bf16.h>
#include <math.h>

#define BATCH 2
#define SEQ   2048
#define DMODEL 1024
#define NHEADS 16
#define HDIM  64
#define MROWS (BATCH*SEQ)   // 4096
#define QSCALE 0.1803368801111204f   // 0.125 * log2(e); attention uses exp2

typedef __attribute__((ext_vector_type(8))) short bfr8;   // 8 bf16 (4 VGPRs)
typedef __attribute__((ext_vector_type(4))) float f32x4;  // MFMA C/D

__device__ inline unsigned short f2bf(float f) {
    union { float f; unsigned u; } v; v.f = f;
    unsigned r = v.u + 0x7FFFu + ((v.u >> 16) & 1u);   // RNE
    return (unsigned short)(r >> 16);
}

__device__ inline unsigned pack2bf(float a, float b) {   // low=a, high=b
    union { __hip_bfloat162 h; unsigned u; } cv;
    cv.h = __float22bfloat162_rn(float2{a, b});
    return cv.u;
}

__device__ inline void gload16(const unsigned short* g, unsigned short* l) {
    __builtin_amdgcn_global_load_lds((const __attribute__((address_space(1))) void*)g,
        (__attribute__((address_space(3))) void*)l, 16, 0, 0);
}

// ---------------- casts fp32 -> bf16 ----------------
__global__ __launch_bounds__(256) void cast_bf16(const float* __restrict__ in,
                                                 unsigned short* __restrict__ out, int n) {
    int i = (blockIdx.x * 256 + threadIdx.x) * 4;
    const int stride = gridDim.x * 256 * 4;
    for (; i < n; i += stride) {
        float4 v = *(const float4*)(in + i);
        ushort4 o;
        o.x = f2bf(v.x); o.y = f2bf(v.y); o.z = f2bf(v.z); o.w = f2bf(v.w);
        *(ushort4*)(out + i) = o;
    }
}

// 4 weight matrices (each 2^20 elems) -> contiguous dst
__global__ __launch_bounds__(256) void cast4_bf16(
    const float* __restrict__ a, const float* __restrict__ b,
    const float* __restrict__ c, const float* __restrict__ d,
    unsigned short* __restrict__ out) {
    const int NW = 1 << 20;
    int i = (blockIdx.x * 256 + threadIdx.x) * 4;
    const int stride = gridDim.x * 256 * 4;
    for (; i < 4 * NW; i += stride) {
        const int seg = i >> 20;
        const float* src = seg == 0 ? a : seg == 1 ? b : seg == 2 ? c : d;
        float4 v = *(const float4*)(src + (i & (NW - 1)));
        ushort4 o;
        o.x = f2bf(v.x); o.y = f2bf(v.y); o.z = f2bf(v.z); o.w = f2bf(v.w);
        *(ushort4*)(out + i) = o;
    }
}

// ---------------- QKV GEMM: 256x256 tile, 8 waves, BK=32 ----------------
// Y = A @ Wcomb^T + bias, A:[4096,1024], Wcomb:[3072,1024].
// 3-buffer LDS (96KB), depth-2 prefetch, SOUND counted-vmcnt sync (R12 pipeline,
// scaled): 32 MFMA/wave per barrier (4x the 128-tile kernel's 8-16).
// Grid 12x16 = 192 blocks = 1/CU, single dispatch round.
// Q scaled by QSCALE; Q,K -> [B,H,T,64]; V -> [B,H,64,T] (transposed).
__global__ __launch_bounds__(512) void gemm_qkv256(
    const unsigned short* __restrict__ A, const unsigned short* __restrict__ W,
    const float* __restrict__ b0, const float* __restrict__ b1,
    const float* __restrict__ b2, unsigned short* __restrict__ Y)
{
    __shared__ __align__(16) unsigned short As[3][4][256][8];  // 48 KB
    __shared__ __align__(16) unsigned short Bs[3][4][256][8];  // 48 KB

    constexpr int NT  = 32;   // K/32
    constexpr int NLD = 4;    // gloads per thread per stage (2 A + 2 B)

    const int tid = threadIdx.x;
    const int l = tid & 63, w = tid >> 6;       // 8 waves
    const int wr = w >> 2, wc = w & 3;          // 2 x 4 -> 128x64 per wave
    const int r15 = l & 15, g2 = l >> 4;        // g2 = 0..3
    const int m0 = blockIdx.y * 256, n0 = blockIdx.x * 256;

    f32x4 acc[8][4] = {};

    auto stage = [&](int buf, int t) {
        const int k0 = t * 32;
        #pragma unroll
        for (int s = 0; s < 2; ++s) {          // A: 1024 granules
            int idx = s * 512 + tid;
            int row = idx & 255, kg = idx >> 8;
            gload16(A + (size_t)(m0 + row) * 1024 + k0 + kg * 8, &As[buf][kg][row][0]);
        }
        #pragma unroll
        for (int s = 0; s < 2; ++s) {          // B: 1024 granules
            int idx = s * 512 + tid;
            int row = idx & 255, kg = idx >> 8;
            gload16(W + (size_t)(n0 + row) * 1024 + k0 + kg * 8, &Bs[buf][kg][row][0]);
        }
    };

    stage(0, 0);
    stage(1, 1);

    for (int t = 0; t < NT; ++t) {
        // each wave waits for ITS OWN tile-t loads, barrier publishes block-wide
        if (t < NT - 1)
            asm volatile("s_waitcnt vmcnt(%0)\ns_barrier" :: "n"(NLD) : "memory");
        else
            asm volatile("s_waitcnt vmcnt(0)\ns_barrier" ::: "memory");
        if (t + 2 < NT) stage((t + 2) % 3, t + 2);

        const int buf = t % 3;
        bfr8 a[8], b[4];
        #pragma unroll
        for (int m = 0; m < 8; ++m)
            a[m] = *(const bfr8*)&As[buf][g2][wr * 128 + m * 16 + r15][0];
        #pragma unroll
        for (int n = 0; n < 4; ++n)
            b[n] = *(const bfr8*)&Bs[buf][g2][wc * 64 + n * 16 + r15][0];
        #pragma unroll
        for (int m = 0; m < 8; ++m)
            #pragma unroll
            for (int n = 0; n < 4; ++n)
                acc[m][n] = __builtin_amdgcn_mfma_f32_16x16x32_bf16(a[m], b[n], acc[m][n], 0, 0, 0);
    }

    const size_t NX = (size_t)MROWS * DMODEL;
    #pragma unroll
    for (int m = 0; m < 8; ++m) {
        const int rowb = m0 + wr * 128 + m * 16 + g2 * 4;
        #pragma unroll
        for (int n = 0; n < 4; ++n) {
            const int col = n0 + wc * 64 + n * 16 + r15;
            const int proj = col >> 10, within = col & 1023;
            const float bc = proj == 0 ? b0[within] : proj == 1 ? b1[within] : b2[within];
            #pragma unroll
            for (int i = 0; i < 4; ++i) {
                float v = acc[m][n][i] + bc;
                if (proj == 0) v *= QSCALE;
                const int rr = rowb + i;
                const int bb = rr >> 11, tt = rr & 2047;
                const int hh = within >> 6, dd = within & 63;
                unsigned short* dst = Y + (size_t)proj * NX;
                size_t idx;
                if (proj < 2)
                    idx = (((size_t)bb * NHEADS + hh) * SEQ + tt) * HDIM + dd;
                else
                    idx = (((size_t)bb * NHEADS + hh) * HDIM + dd) * SEQ + tt;
                dst[idx] = f2bf(v);
            }
        }
    }
}

// ---------------- output GEMM: BM=64 x 128, 4 waves (proven R12 pipeline) ----------------
__global__ __launch_bounds__(256) void gemm_out(
    const unsigned short* __restrict__ A, const unsigned short* __restrict__ W,
    const float* __restrict__ b0, float* __restrict__ Y)
{
    __shared__ __align__(16) unsigned short As[3][4][64][8];
    __shared__ __align__(16) unsigned short Bs[3][4][128][8];

    constexpr int NT  = 32;
    constexpr int NLD = 3;   // 1 A + 2 B

    const int tid = threadIdx.x;
    const int l = tid & 63, w = tid >> 6;
    const int wr = w >> 1, wc = w & 1;
    const int m0 = blockIdx.y * 64, n0 = blockIdx.x * 128;
    const int r15 = l & 15, g = l >> 4;

    f32x4 acc[2][4] = {};

    auto stage = [&](int buf, int t) {
        const int k0 = t * 32;
        {
            int idx = tid;                      // A: 256 granules
            int row = idx & 63, kg = idx >> 6;
            gload16(A + (size_t)(m0 + row) * 1024 + k0 + kg * 8, &As[buf][kg][row][0]);
        }
        #pragma unroll
        for (int s = 0; s < 2; ++s) {           // B: 512 granules
            int idx = s * 256 + tid;
            int row = idx & 127, kg = idx >> 7;
            gload16(W + (size_t)(n0 + row) * 1024 + k0 + kg * 8, &Bs[buf][kg][row][0]);
        }
    };

    stage(0, 0);
    stage(1, 1);

    for (int t = 0; t < NT; ++t) {
        if (t < NT - 1)
            asm volatile("s_waitcnt vmcnt(%0)\ns_barrier" :: "n"(NLD) : "memory");
        else
            asm volatile("s_waitcnt vmcnt(0)\ns_barrier" ::: "memory");
        if (t + 2 < NT) stage((t + 2) % 3, t + 2);

        const int buf = t % 3;
        bfr8 a[2], b[4];
        #pragma unroll
        for (int m = 0; m < 2; ++m)
            a[m] = *(const bfr8*)&As[buf][g][wr * 32 + m * 16 + r15][0];
        #pragma unroll
        for (int n = 0; n < 4; ++n)
            b[n] = *(const bfr8*)&Bs[buf][g][wc * 64 + n * 16 + r15][0];
        #pragma unroll
        for (int m = 0; m < 2; ++m)
            #pragma unroll
            for (int n = 0; n < 4; ++n)
                acc[m][n] = __builtin_amdgcn_mfma_f32_16x16x32_bf16(a[m], b[n], acc[m][n], 0, 0, 0);
    }

    #pragma unroll
    for (int m = 0; m < 2; ++m) {
        const int rowb = m0 + wr * 32 + m * 16 + g * 4;
        #pragma unroll
        for (int n = 0; n < 4; ++n) {
            const int col = n0 + wc * 64 + n * 16 + r15;
            const float bc = b0[col];
            #pragma unroll
            for (int i = 0; i < 4; ++i)
                Y[(size_t)(rowb + i) * 1024 + col] = acc[m][n][i] + bc;
        }
    }
}

// ---------------- MFMA flash attention (causal, fully lane-local softmax) ----------------
// [R6 structure EXACT: 2-buffer, 40KB LDS, 4 blocks/CU, __syncthreads drain]
__global__ __launch_bounds__(256, 4) void attn_mfma(
    const unsigned short* __restrict__ Q, const unsigned short* __restrict__ K,
    const unsigned short* __restrict__ VT, unsigned short* __restrict__ O)
{
    __shared__ __align__(16) unsigned short Ks[2][64][64];   // [kv][d] granule-swizzled (16K)
    __shared__ __align__(16) unsigned short Vs[2][64][64];   // [d][kv] granule-swizzled (16K)
    __shared__ __align__(16) unsigned short Ps[4][8][16][8]; // [wave][kg][q][e]  (8K)

    const int tid = threadIdx.x;
    const int l = tid & 63, w = tid >> 6;
    const int r15 = l & 15, g2 = l >> 4;          // g2 = 0..3
    const int qt = (blockIdx.x + blockIdx.y) & 31;   // decorrelate length from CU
    const int q0 = SEQ - 64 - qt * 64;
    const int q  = q0 + w * 16 + r15;             // this lane's q column
    const int bh = blockIdx.y;

    const unsigned short* Qb = Q + (size_t)bh * SEQ * HDIM;
    const unsigned short* Kb = K + (size_t)bh * SEQ * HDIM;
    const unsigned short* Vb = VT + (size_t)bh * HDIM * SEQ;

    bfr8 qf[2];
    qf[0] = *(const bfr8*)(Qb + (size_t)q * HDIM + g2 * 8);
    qf[1] = *(const bfr8*)(Qb + (size_t)q * HDIM + 32 + g2 * 8);

    auto stage = [&](int buf, int kv0) {
        #pragma unroll
        for (int s = 0; s < 2; ++s) {
            int idx = s * 256 + tid;               // 512 granules each of K, V
            int row = idx >> 3, gs = idx & 7;
            gload16(Kb + (size_t)(kv0 + row) * HDIM + ((gs ^ (row & 7)) * 8), &Ks[buf][row][gs * 8]);
            gload16(Vb + (size_t)row * SEQ + kv0 + ((gs ^ (row & 7)) * 8), &Vs[buf][row][gs * 8]);
        }
    };

    f32x4 o[4] = {};                 // o[ch][i]: d = ch*16 + g2*4 + i, col q
    float m = -INFINITY, rden = 0.f;

    const int ntiles = q0 / 64 + 1;
    stage(0, 0);
    __syncthreads();

    for (int kt = 0; kt < ntiles; ++kt) {
        const int kv0 = kt * 64, buf = kt & 1;
        if (kt + 1 < ntiles) stage(buf ^ 1, kv0 + 64);

        // ---- S^T = K @ Q^T : s[c][i], kv = c*16 + g2*4 + i, q = col r15 ----
        f32x4 s[4];
        #pragma unroll
        for (int c = 0; c < 4; ++c) {
            const int rk = c * 16 + r15;
            const bfr8 kf0 = *(const bfr8*)&Ks[buf][rk][(g2 ^ (r15 & 7)) * 8];
            const bfr8 kf1 = *(const bfr8*)&Ks[buf][rk][((4 + g2) ^ (r15 & 7)) * 8];
            f32x4 z = {0.f, 0.f, 0.f, 0.f};
            z = __builtin_amdgcn_mfma_f32_16x16x32_bf16(kf0, qf[0], z, 0, 0, 0);
            s[c] = __builtin_amdgcn_mfma_f32_16x16x32_bf16(kf1, qf[1], z, 0, 0, 0);
        }

        if (kt == ntiles - 1) {      // causal mask: only the diagonal tile
            #pragma unroll
            for (int c = 0; c < 4; ++c)
                #pragma unroll
                for (int i = 0; i < 4; ++i)
                    if (kv0 + c * 16 + g2 * 4 + i > q) s[c][i] = -INFINITY;
        }

        // ---- lane-local online softmax with defer-max ----
        float tm = s[0][0];
        #pragma unroll
        for (int c = 0; c < 4; ++c)
            #pragma unroll
            for (int i = 0; i < 4; ++i) tm = fmaxf(tm, s[c][i]);
        tm = fmaxf(tm, __shfl_xor(tm, 16));
        tm = fmaxf(tm, __shfl_xor(tm, 32));
        if (__any(tm > m + 8.f)) {            // rescale (always taken on first tile)
            const float mn = fmaxf(m, tm);
            const float scl = exp2f(m - mn);  // 0 on first tile
            m = mn;
            rden *= scl;
            #pragma unroll
            for (int ch = 0; ch < 4; ++ch)
                #pragma unroll
                for (int i = 0; i < 4; ++i) o[ch][i] *= scl;
        }
        float ls = 0.f;
        #pragma unroll
        for (int c = 0; c < 4; ++c)
            #pragma unroll
            for (int i = 0; i < 4; ++i) {
                const float p = exp2f(s[c][i] - m);
                s[c][i] = p;
                ls += p;
            }
        ls += __shfl_xor(ls, 16);
        ls += __shfl_xor(ls, 32);
        rden += ls;

        // ---- P -> LDS in B-frag layout: Ps[kg][q][e] = P[kv=kg*8+e][q] ----
        {
            const int eb = (g2 & 1) * 4;
            #pragma unroll
            for (int c = 0; c < 4; ++c) {
                const int kg = c * 2 + (g2 >> 1);
                *(unsigned*)&Ps[w][kg][r15][eb]     = pack2bf(s[c][0], s[c][1]);
                *(unsigned*)&Ps[w][kg][r15][eb + 2] = pack2bf(s[c][2], s[c][3]);
            }
        }
        // wave-private buffer: within-wave lgkmcnt ordering suffices (no barrier)
        bfr8 pf[2];
        pf[0] = *(const bfr8*)&Ps[w][g2][r15][0];
        pf[1] = *(const bfr8*)&Ps[w][4 + g2][r15][0];

        // ---- O' += V^T @ P ----
        #pragma unroll
        for (int ch = 0; ch < 4; ++ch) {
            const int d = ch * 16 + r15;
            const bfr8 vf0 = *(const bfr8*)&Vs[buf][d][(g2 ^ (r15 & 7)) * 8];
            const bfr8 vf1 = *(const bfr8*)&Vs[buf][d][((4 + g2) ^ (r15 & 7)) * 8];
            o[ch] = __builtin_amdgcn_mfma_f32_16x16x32_bf16(vf0, pf[0], o[ch], 0, 0, 0);
            o[ch] = __builtin_amdgcn_mfma_f32_16x16x32_bf16(vf1, pf[1], o[ch], 0, 0, 0);
        }
        __syncthreads();   // protect K/V buffers (also drains staged loads)
    }

    const float inv = 1.f / rden;
    const int b = bh >> 4, h = bh & 15;
    unsigned short* Ob = O + ((size_t)b * SEQ + q) * DMODEL + h * HDIM + g2 * 4;
    #pragma unroll
    for (int ch = 0; ch < 4; ++ch) {
        uint2 pk;
        pk.x = pack2bf(o[ch][0] * inv, o[ch][1] * inv);
        pk.y = pack2bf(o[ch][2] * inv, o[ch][3] * inv);
        *(uint2*)(Ob + ch * 16) = pk;
    }
}

// ---------------- launch ----------------
extern "C" void kernel_launch(void* const* d_in, const int* in_sizes, int n_in,
                              void* d_out, int out_size, void* d_ws, size_t ws_size,
                              hipStream_t stream) {
    const float* x   = (const float*)d_in[0];
    const float* w_q = (const float*)d_in[1];
    const float* b_q = (const float*)d_in[2];
    const float* w_k = (const float*)d_in[3];
    const float* b_k = (const float*)d_in[4];
    const float* w_v = (const float*)d_in[5];
    const float* b_v = (const float*)d_in[6];
    const float* w_o = (const float*)d_in[7];
    const float* b_o = (const float*)d_in[8];
    float* out = (float*)d_out;

    const size_t NX = (size_t)MROWS * DMODEL;   // 4,194,304
    const size_t NW = (size_t)DMODEL * DMODEL;  // 1,048,576 = 2^20
    unsigned short* xb    = (unsigned short*)d_ws;
    unsigned short* wcomb = xb + NX;            // [3072][1024] = wq|wk|wv, then wo
    unsigned short* wob   = wcomb + 3 * NW;
    unsigned short* Qw    = wob + NW;           // [B,H,T,64] (scaled)
    unsigned short* Kw    = Qw + NX;            // [B,H,T,64]
    unsigned short* VTw   = Kw + NX;            // [B,H,64,T]
    unsigned short* Ow    = VTw + NX;           // [B,T,1024]

    cast_bf16<<<1024, 256, 0, stream>>>(x, xb, (int)NX);
    cast4_bf16<<<2048, 256, 0, stream>>>(w_q, w_k, w_v, w_o, wcomb);

    // fused QKV projection: 256x256 tiles, 192 blocks (1/CU)
    gemm_qkv256<<<dim3(12, 16), 512, 0, stream>>>(xb, wcomb, b_q, b_k, b_v, Qw);

    attn_mfma<<<dim3(32, 32), 256, 0, stream>>>(Qw, Kw, VTw, Ow);

    // output projection: [4096,1024] @ [1024,1024]^T -> fp32
    gemm_out<<<dim3(8, 64), 256, 0, stream>>>(Ow, wob, b_o, out);
}

// Round 14
// 161.373 us; speedup vs baseline: 1.5699x; 1.1441x over previous
//
#include <hip/hip_runtime.h>
#include <hip/hip_bf16.h>
#include <math.h>

#define BATCH 2
#define SEQ   2048
#define DMODEL 1024
#define NHEADS 16
#define HDIM  64
#define MROWS (BATCH*SEQ)   // 4096
#define QSCALE 0.1803368801111204f   // 0.125 * log2(e); attention uses exp2

typedef __attribute__((ext_vector_type(8))) short bfr8;   // 8 bf16 (4 VGPRs)
typedef __attribute__((ext_vector_type(4))) float f32x4;  // MFMA C/D

__device__ inline unsigned short f2bf(float f) {
    union { float f; unsigned u; } v; v.f = f;
    unsigned r = v.u + 0x7FFFu + ((v.u >> 16) & 1u);   // RNE
    return (unsigned short)(r >> 16);
}

__device__ inline unsigned pack2bf(float a, float b) {   // low=a, high=b
    union { __hip_bfloat162 h; unsigned u; } cv;
    cv.h = __float22bfloat162_rn(float2{a, b});
    return cv.u;
}

__device__ inline void gload16(const unsigned short* g, unsigned short* l) {
    __builtin_amdgcn_global_load_lds((const __attribute__((address_space(1))) void*)g,
        (__attribute__((address_space(3))) void*)l, 16, 0, 0);
}

// ---------------- single fused cast: x + 4 weights -> bf16 contiguous ----------------
__global__ __launch_bounds__(256) void cast_all(
    const float* __restrict__ x,  const float* __restrict__ wq,
    const float* __restrict__ wk, const float* __restrict__ wv,
    const float* __restrict__ wo, unsigned short* __restrict__ out) {
    const int NX4 = 4 << 20, NW = 1 << 20, TOT = 8 << 20;
    int i = (blockIdx.x * 256 + threadIdx.x) * 4;
    const int stride = gridDim.x * 256 * 4;
    for (; i < TOT; i += stride) {
        const float* src; int off;
        if (i < NX4) { src = x; off = i; }
        else {
            const int seg = (i - NX4) >> 20;
            src = seg == 0 ? wq : seg == 1 ? wk : seg == 2 ? wv : wo;
            off = i & (NW - 1);
        }
        float4 v = *(const float4*)(src + off);
        ushort4 o;
        o.x = f2bf(v.x); o.y = f2bf(v.y); o.z = f2bf(v.z); o.w = f2bf(v.w);
        *(ushort4*)(out + i) = o;
    }
}

// ---------------- bf16 MFMA GEMM: Y = A @ W^T + bias ----------------
// R6-proven structure: tile BM x 128, BK=32, 4 waves, 2-buffer LDS (32KB),
// stage-ahead + __syncthreads. + bijective XCD rect remap (R9: -2MB FETCH).
// MODE 0: N=3072 fused QKV; Q scaled by QSCALE; Q,K->[B,H,T,64], V->[B,H,64,T]
// MODE 2: N=1024, fp32 linear output [4096,1024], bias b0
template<int BM, int MODE>
__global__ __launch_bounds__(256) void gemm_bf16(
    const unsigned short* __restrict__ A, const unsigned short* __restrict__ W,
    const float* __restrict__ b0, const float* __restrict__ b1,
    const float* __restrict__ b2, void* __restrict__ Y)
{
    __shared__ __align__(16) unsigned short As[2][4][BM][8];
    __shared__ __align__(16) unsigned short Bs[2][4][128][8];

    constexpr int NT = 32;             // K / 32

    const int tid = threadIdx.x;
    const int l = tid & 63, w = tid >> 6;
    const int wr = w >> 1, wc = w & 1;
    const int r15 = l & 15, g = l >> 4;
    constexpr int MR = BM / 32;

    // bijective XCD rect remap for L2 locality
    int bx, by;
    if (MODE == 0) {                   // grid 24 x 32: 12x8 rect per XCD
        const int flat = blockIdx.x + blockIdx.y * 24;
        const int xcd = flat & 7, s = flat >> 3;        // s in [0,96)
        bx = (xcd & 1) * 12 + s % 12;
        by = (xcd >> 1) * 8 + s / 12;
    } else {                           // grid 8 x 64: 8x8 rect per XCD
        const int flat = blockIdx.x + blockIdx.y * 8;
        const int xcd = flat & 7, s = flat >> 3;        // s in [0,64)
        bx = s & 7;
        by = xcd * 8 + (s >> 3);
    }
    const int m0 = by * BM, n0 = bx * 128;

    f32x4 acc[MR][4] = {};

    auto stage = [&](int buf, int t) {
        const int k0 = t * 32;
        #pragma unroll
        for (int s = 0; s < BM / 64; ++s) {
            int idx = s * 256 + tid;
            int row = idx % BM, kg = idx / BM;
            gload16(A + (size_t)(m0 + row) * 1024 + k0 + kg * 8, &As[buf][kg][row][0]);
        }
        #pragma unroll
        for (int s = 0; s < 2; ++s) {
            int idx = s * 256 + tid;
            int row = idx & 127, kg = idx >> 7;
            gload16(W + (size_t)(n0 + row) * 1024 + k0 + kg * 8, &Bs[buf][kg][row][0]);
        }
    };

    stage(0, 0);
    __syncthreads();

    for (int t = 0; t < NT; ++t) {
        const int buf = t & 1;
        if (t + 1 < NT) stage(buf ^ 1, t + 1);
        bfr8 a[MR], b[4];
        #pragma unroll
        for (int m = 0; m < MR; ++m)
            a[m] = *(const bfr8*)&As[buf][g][wr * (BM / 2) + m * 16 + r15][0];
        #pragma unroll
        for (int n = 0; n < 4; ++n)
            b[n] = *(const bfr8*)&Bs[buf][g][wc * 64 + n * 16 + r15][0];
        #pragma unroll
        for (int m = 0; m < MR; ++m)
            #pragma unroll
            for (int n = 0; n < 4; ++n)
                acc[m][n] = __builtin_amdgcn_mfma_f32_16x16x32_bf16(a[m], b[n], acc[m][n], 0, 0, 0);
        __syncthreads();
    }

    const size_t NX = (size_t)MROWS * DMODEL;
    #pragma unroll
    for (int m = 0; m < MR; ++m) {
        const int rowb = m0 + wr * (BM / 2) + m * 16 + g * 4;
        #pragma unroll
        for (int n = 0; n < 4; ++n) {
            const int col = n0 + wc * 64 + n * 16 + r15;
            const int proj = col >> 10, within = col & 1023;
            const float bc = (MODE == 2) ? b0[col]
                           : (proj == 0 ? b0[within] : proj == 1 ? b1[within] : b2[within]);
            #pragma unroll
            for (int i = 0; i < 4; ++i) {
                float v = acc[m][n][i] + bc;
                const int rr = rowb + i;
                if (MODE == 2) {
                    ((float*)Y)[(size_t)rr * 1024 + col] = v;
                } else {
                    if (proj == 0) v *= QSCALE;
                    const int bb = rr >> 11, tt = rr & 2047;
                    const int hh = within >> 6, dd = within & 63;
                    unsigned short* dst = (unsigned short*)Y + (size_t)proj * NX;
                    size_t idx;
                    if (proj < 2)
                        idx = (((size_t)bb * NHEADS + hh) * SEQ + tt) * HDIM + dd;
                    else
                        idx = (((size_t)bb * NHEADS + hh) * HDIM + dd) * SEQ + tt;
                    dst[idx] = f2bf(v);
                }
            }
        }
    }
}

// ---------------- MFMA flash attention (causal, fully lane-local softmax) ----------------
// [R6 structure EXACT: 2-buffer, 40KB LDS, 4 blocks/CU, __syncthreads drain — ~40µs]
__global__ __launch_bounds__(256, 4) void attn_mfma(
    const unsigned short* __restrict__ Q, const unsigned short* __restrict__ K,
    const unsigned short* __restrict__ VT, unsigned short* __restrict__ O)
{
    __shared__ __align__(16) unsigned short Ks[2][64][64];   // [kv][d] granule-swizzled (16K)
    __shared__ __align__(16) unsigned short Vs[2][64][64];   // [d][kv] granule-swizzled (16K)
    __shared__ __align__(16) unsigned short Ps[4][8][16][8]; // [wave][kg][q][e]  (8K)

    const int tid = threadIdx.x;
    const int l = tid & 63, w = tid >> 6;
    const int r15 = l & 15, g2 = l >> 4;          // g2 = 0..3
    const int qt = (blockIdx.x + blockIdx.y) & 31;   // decorrelate length from CU
    const int q0 = SEQ - 64 - qt * 64;
    const int q  = q0 + w * 16 + r15;             // this lane's q column
    const int bh = blockIdx.y;

    const unsigned short* Qb = Q + (size_t)bh * SEQ * HDIM;
    const unsigned short* Kb = K + (size_t)bh * SEQ * HDIM;
    const unsigned short* Vb = VT + (size_t)bh * HDIM * SEQ;

    bfr8 qf[2];
    qf[0] = *(const bfr8*)(Qb + (size_t)q * HDIM + g2 * 8);
    qf[1] = *(const bfr8*)(Qb + (size_t)q * HDIM + 32 + g2 * 8);

    auto stage = [&](int buf, int kv0) {
        #pragma unroll
        for (int s = 0; s < 2; ++s) {
            int idx = s * 256 + tid;               // 512 granules each of K, V
            int row = idx >> 3, gs = idx & 7;
            gload16(Kb + (size_t)(kv0 + row) * HDIM + ((gs ^ (row & 7)) * 8), &Ks[buf][row][gs * 8]);
            gload16(Vb + (size_t)row * SEQ + kv0 + ((gs ^ (row & 7)) * 8), &Vs[buf][row][gs * 8]);
        }
    };

    f32x4 o[4] = {};                 // o[ch][i]: d = ch*16 + g2*4 + i, col q
    float m = -INFINITY, rden = 0.f;

    const int ntiles = q0 / 64 + 1;
    stage(0, 0);
    __syncthreads();

    for (int kt = 0; kt < ntiles; ++kt) {
        const int kv0 = kt * 64, buf = kt & 1;
        if (kt + 1 < ntiles) stage(buf ^ 1, kv0 + 64);

        // ---- S^T = K @ Q^T : s[c][i], kv = c*16 + g2*4 + i, q = col r15 ----
        f32x4 s[4];
        #pragma unroll
        for (int c = 0; c < 4; ++c) {
            const int rk = c * 16 + r15;
            const bfr8 kf0 = *(const bfr8*)&Ks[buf][rk][(g2 ^ (r15 & 7)) * 8];
            const bfr8 kf1 = *(const bfr8*)&Ks[buf][rk][((4 + g2) ^ (r15 & 7)) * 8];
            f32x4 z = {0.f, 0.f, 0.f, 0.f};
            z = __builtin_amdgcn_mfma_f32_16x16x32_bf16(kf0, qf[0], z, 0, 0, 0);
            s[c] = __builtin_amdgcn_mfma_f32_16x16x32_bf16(kf1, qf[1], z, 0, 0, 0);
        }

        if (kt == ntiles - 1) {      // causal mask: only the diagonal tile
            #pragma unroll
            for (int c = 0; c < 4; ++c)
                #pragma unroll
                for (int i = 0; i < 4; ++i)
                    if (kv0 + c * 16 + g2 * 4 + i > q) s[c][i] = -INFINITY;
        }

        // ---- lane-local online softmax with defer-max ----
        float tm = s[0][0];
        #pragma unroll
        for (int c = 0; c < 4; ++c)
            #pragma unroll
            for (int i = 0; i < 4; ++i) tm = fmaxf(tm, s[c][i]);
        tm = fmaxf(tm, __shfl_xor(tm, 16));
        tm = fmaxf(tm, __shfl_xor(tm, 32));
        if (__any(tm > m + 8.f)) {            // rescale (always taken on first tile)
            const float mn = fmaxf(m, tm);
            const float scl = exp2f(m - mn);  // 0 on first tile
            m = mn;
            rden *= scl;
            #pragma unroll
            for (int ch = 0; ch < 4; ++ch)
                #pragma unroll
                for (int i = 0; i < 4; ++i) o[ch][i] *= scl;
        }
        float ls = 0.f;
        #pragma unroll
        for (int c = 0; c < 4; ++c)
            #pragma unroll
            for (int i = 0; i < 4; ++i) {
                const float p = exp2f(s[c][i] - m);
                s[c][i] = p;
                ls += p;
            }
        ls += __shfl_xor(ls, 16);
        ls += __shfl_xor(ls, 32);
        rden += ls;

        // ---- P -> LDS in B-frag layout: Ps[kg][q][e] = P[kv=kg*8+e][q] ----
        {
            const int eb = (g2 & 1) * 4;
            #pragma unroll
            for (int c = 0; c < 4; ++c) {
                const int kg = c * 2 + (g2 >> 1);
                *(unsigned*)&Ps[w][kg][r15][eb]     = pack2bf(s[c][0], s[c][1]);
                *(unsigned*)&Ps[w][kg][r15][eb + 2] = pack2bf(s[c][2], s[c][3]);
            }
        }
        // wave-private buffer: within-wave lgkmcnt ordering suffices (no barrier)
        bfr8 pf[2];
        pf[0] = *(const bfr8*)&Ps[w][g2][r15][0];
        pf[1] = *(const bfr8*)&Ps[w][4 + g2][r15][0];

        // ---- O' += V^T @ P ----
        #pragma unroll
        for (int ch = 0; ch < 4; ++ch) {
            const int d = ch * 16 + r15;
            const bfr8 vf0 = *(const bfr8*)&Vs[buf][d][(g2 ^ (r15 & 7)) * 8];
            const bfr8 vf1 = *(const bfr8*)&Vs[buf][d][((4 + g2) ^ (r15 & 7)) * 8];
            o[ch] = __builtin_amdgcn_mfma_f32_16x16x32_bf16(vf0, pf[0], o[ch], 0, 0, 0);
            o[ch] = __builtin_amdgcn_mfma_f32_16x16x32_bf16(vf1, pf[1], o[ch], 0, 0, 0);
        }
        __syncthreads();   // protect K/V buffers (also drains staged loads)
    }

    const float inv = 1.f / rden;
    const int b = bh >> 4, h = bh & 15;
    unsigned short* Ob = O + ((size_t)b * SEQ + q) * DMODEL + h * HDIM + g2 * 4;
    #pragma unroll
    for (int ch = 0; ch < 4; ++ch) {
        uint2 pk;
        pk.x = pack2bf(o[ch][0] * inv, o[ch][1] * inv);
        pk.y = pack2bf(o[ch][2] * inv, o[ch][3] * inv);
        *(uint2*)(Ob + ch * 16) = pk;
    }
}

// ---------------- launch ----------------
extern "C" void kernel_launch(void* const* d_in, const int* in_sizes, int n_in,
                              void* d_out, int out_size, void* d_ws, size_t ws_size,
                              hipStream_t stream) {
    const float* x   = (const float*)d_in[0];
    const float* w_q = (const float*)d_in[1];
    const float* b_q = (const float*)d_in[2];
    const float* w_k = (const float*)d_in[3];
    const float* b_k = (const float*)d_in[4];
    const float* w_v = (const float*)d_in[5];
    const float* b_v = (const float*)d_in[6];
    const float* w_o = (const float*)d_in[7];
    const float* b_o = (const float*)d_in[8];
    float* out = (float*)d_out;

    const size_t NX = (size_t)MROWS * DMODEL;   // 4,194,304
    const size_t NW = (size_t)DMODEL * DMODEL;  // 1,048,576 = 2^20
    unsigned short* xb    = (unsigned short*)d_ws;
    unsigned short* wcomb = xb + NX;            // [3072][1024] = wq|wk|wv
    unsigned short* wob   = wcomb + 3 * NW;     // [1024][1024]
    unsigned short* Qw    = wob + NW;           // [B,H,T,64] (scaled)
    unsigned short* Kw    = Qw + NX;            // [B,H,T,64]
    unsigned short* VTw   = Kw + NX;            // [B,H,64,T]
    unsigned short* Ow    = VTw + NX;           // [B,T,1024]

    // one cast kernel: x|wq|wk|wv|wo -> bf16 at xb (contiguous 8M elems)
    cast_all<<<2048, 256, 0, stream>>>(x, w_q, w_k, w_v, w_o, xb);

    // fused QKV projection: [4096,1024] @ [3072,1024]^T
    gemm_bf16<128, 0><<<dim3(24, 32), 256, 0, stream>>>(xb, wcomb, b_q, b_k, b_v, Qw);

    attn_mfma<<<dim3(32, 32), 256, 0, stream>>>(Qw, Kw, VTw, Ow);

    // output projection: [4096,1024] @ [1024,1024]^T -> fp32
    gemm_bf16<64, 2><<<dim3(8, 64), 256, 0, stream>>>(Ow, wob, b_o, nullptr, nullptr, out);
}